// Round 5
// baseline (273.736 us; speedup 1.0000x reference)
//
#include <hip/hip_runtime.h>

#define NODES 10000
#define BATCH 8
#define CH    128
#define KNB   16
#define CO    256

typedef __bf16 bf16x8 __attribute__((ext_vector_type(8)));
typedef float  f32x4  __attribute__((ext_vector_type(4)));

__device__ __forceinline__ unsigned short f2bf(float f) {
  unsigned u = __float_as_uint(f);
  u = (u + 0x7FFFu + ((u >> 16) & 1u)) >> 16;   // RNE
  return (unsigned short)u;
}

// max of packed non-negative bf16 == packed u16 max (relu guarantees >=0)
__device__ __forceinline__ unsigned pkmax(unsigned a, unsigned b) {
  unsigned d;
  asm("v_pk_max_u16 %0, %1, %2" : "=v"(d) : "v"(a), "v"(b));
  return d;
}
__device__ __forceinline__ uint4 pkmax4(uint4 a, uint4 b) {
  a.x = pkmax(a.x, b.x); a.y = pkmax(a.y, b.y);
  a.z = pkmax(a.z, b.z); a.w = pkmax(a.w, b.w);
  return a;
}
__device__ __forceinline__ bf16x8 asbf8(uint4 u) {
  union { uint4 u; bf16x8 b; } c; c.u = u; return c.b;
}

// ---------------------------------------------------------------------------
// fp32 -> bf16 weight conversion (row-major [d][k] kept)
// ---------------------------------------------------------------------------
__global__ __launch_bounds__(256) void prep(
    const float* __restrict__ W1, const float* __restrict__ Wp,
    const float* __restrict__ W2,
    unsigned short* __restrict__ W1b, unsigned short* __restrict__ Wpb,
    unsigned short* __restrict__ W2b)
{
  int i = blockIdx.x * 256 + threadIdx.x;   // float4 index, 24576 total
  const float* src; unsigned short* dst; int off;
  if (i < 4096)      { src = W1; dst = W1b; off = i; }
  else if (i < 8192) { src = Wp; dst = Wpb; off = i - 4096; }
  else               { src = W2; dst = W2b; off = i - 8192; }
  float4 v = ((const float4*)src)[off];
  ushort4 o;
  o.x = f2bf(v.x); o.y = f2bf(v.y); o.z = f2bf(v.z); o.w = f2bf(v.w);
  ((ushort4*)dst)[off] = o;
}

// ---------------------------------------------------------------------------
// Fused: h = relu(W1 x + b1); z = relu(Wp h + bp), node-major bf16 [b][n][128].
// v2 (kept from R4): global stores go through LDS repack -> 64B-per-quad
// contiguous writes.
// ---------------------------------------------------------------------------
__global__ __launch_bounds__(256) void fused_hz(
    const unsigned short* __restrict__ W1b, const float* __restrict__ b1,
    const unsigned short* __restrict__ Wpb, const float* __restrict__ bp,
    const float* __restrict__ x,
    unsigned short* __restrict__ h_t, unsigned short* __restrict__ z_t)
{
  const int b  = blockIdx.y;
  const int n0 = blockIdx.x * 64;
  const int t  = threadIdx.x;
  const int lane = t & 63, w = t >> 6;
  const int lm = lane & 15, q = lane >> 4;
  const size_t nb = (size_t)b * NODES;

  __shared__ __align__(16) unsigned short Bt[64 * 128];   // x tile, 16 KB
  __shared__ __align__(16) unsigned short Ht[64 * 128];   // h tile, 16 KB
  char* BtB = (char*)Bt;
  char* HtB = (char*)Ht;

  // ---- stage x: fp32 [b][c][n] -> bf16 [n][c], XOR-swizzled 16B chunks
  {
    const float* X = x + (size_t)b * CH * NODES;
#pragma unroll
    for (int rep = 0; rep < 4; ++rep) {
      int flat = t + rep * 256;
      int c2 = flat >> 4, n4 = flat & 15;
      int c  = c2 * 2;
      int gn = n0 + n4 * 4;
      float4 a0 = make_float4(0.f,0.f,0.f,0.f), a1 = a0;
      if (gn < NODES) {
        a0 = *(const float4*)(X + (size_t)c * NODES + gn);
        a1 = *(const float4*)(X + (size_t)(c + 1) * NODES + gn);
      }
      float v0[4] = {a0.x, a0.y, a0.z, a0.w};
      float v1[4] = {a1.x, a1.y, a1.z, a1.w};
#pragma unroll
      for (int i = 0; i < 4; ++i) {
        int nn = n4 * 4 + i;
        unsigned pk = (unsigned)f2bf(v0[i]) | ((unsigned)f2bf(v1[i]) << 16);
        int phys = nn * 256 + (((c2 >> 2) ^ (nn & 7)) << 4) + ((c2 & 3) << 2);
        *(unsigned*)(BtB + phys) = pk;
      }
    }
  }

  const int d0  = (w & 1) * 64;      // d-half for this wave
  const int nbw = (w >> 1) * 32;     // node-pair base

  // W1 A-fragments (global, L2-hot)
  uint4 af[4][4];
#pragma unroll
  for (int dt = 0; dt < 4; ++dt)
#pragma unroll
    for (int kt = 0; kt < 4; ++kt)
      af[dt][kt] = *(const uint4*)(W1b + (d0 + dt*16 + lm) * CH + kt*32 + q*8);

  __syncthreads();   // barrier 1: Bt staged

  // ---- phase 1 MFMA: h-tile
  f32x4 acc[4][2];
#pragma unroll
  for (int dt = 0; dt < 4; ++dt)
#pragma unroll
    for (int nt = 0; nt < 2; ++nt) acc[dt][nt] = (f32x4){0.f,0.f,0.f,0.f};

#pragma unroll
  for (int kt = 0; kt < 4; ++kt)
#pragma unroll
    for (int nt = 0; nt < 2; ++nt) {
      int nl = nbw + nt * 16 + lm;
      int chunk = kt * 4 + q;
      int phys = nl * 256 + ((chunk ^ (nl & 7)) << 4);
      bf16x8 bb = asbf8(*(const uint4*)(BtB + phys));
#pragma unroll
      for (int dt = 0; dt < 4; ++dt)
        acc[dt][nt] = __builtin_amdgcn_mfma_f32_16x16x32_bf16(
            asbf8(af[dt][kt]), bb, acc[dt][nt], 0, 0, 0);
    }

  // Wp A-fragments for phase 2 (issue loads before the barrier)
  uint4 af2[4][4];
#pragma unroll
  for (int dt = 0; dt < 4; ++dt)
#pragma unroll
    for (int kt = 0; kt < 4; ++kt)
      af2[dt][kt] = *(const uint4*)(Wpb + (d0 + dt*16 + lm) * CH + kt*32 + q*8);

  // ---- epilogue 1: bias+relu+bf16 -> Ht LDS only (B-frag layout)
#pragma unroll
  for (int dt = 0; dt < 4; ++dt) {
    int dbase = d0 + dt * 16 + q * 4;
    float4 bi = *(const float4*)(b1 + dbase);
    float bv[4] = {bi.x, bi.y, bi.z, bi.w};
#pragma unroll
    for (int nt = 0; nt < 2; ++nt) {
      int nl = nbw + nt * 16 + lm;
      ushort4 o;
      o.x = f2bf(fmaxf(acc[dt][nt][0] + bv[0], 0.f));
      o.y = f2bf(fmaxf(acc[dt][nt][1] + bv[1], 0.f));
      o.z = f2bf(fmaxf(acc[dt][nt][2] + bv[2], 0.f));
      o.w = f2bf(fmaxf(acc[dt][nt][3] + bv[3], 0.f));
      int chunk = dbase >> 3;
      int phys  = nl * 256 + ((chunk ^ (nl & 7)) << 4) + ((q & 1) << 3);
      *(ushort4*)(HtB + phys) = o;
    }
  }

  __syncthreads();   // barrier 2: Ht complete

  // ---- coalesced h_t write: quad (nl = t>>2, g = t&3 + 4*rep) -> 64B/quad
  {
    int nl = t >> 2;
    int gn = n0 + nl;
#pragma unroll
    for (int rep = 0; rep < 4; ++rep) {
      int g = (t & 3) + rep * 4;
      int phys = nl * 256 + ((g ^ (nl & 7)) << 4);
      uint4 v = *(const uint4*)(HtB + phys);
      if (gn < NODES)
        *(uint4*)((char*)h_t + (nb + (size_t)gn) * 256 + g * 16) = v;
    }
  }

  // ---- phase 2 MFMA: z-tile from Ht
#pragma unroll
  for (int dt = 0; dt < 4; ++dt)
#pragma unroll
    for (int nt = 0; nt < 2; ++nt) acc[dt][nt] = (f32x4){0.f,0.f,0.f,0.f};

#pragma unroll
  for (int kt = 0; kt < 4; ++kt)
#pragma unroll
    for (int nt = 0; nt < 2; ++nt) {
      int nl = nbw + nt * 16 + lm;
      int chunk = kt * 4 + q;
      int phys = nl * 256 + ((chunk ^ (nl & 7)) << 4);
      bf16x8 bb = asbf8(*(const uint4*)(HtB + phys));
#pragma unroll
      for (int dt = 0; dt < 4; ++dt)
        acc[dt][nt] = __builtin_amdgcn_mfma_f32_16x16x32_bf16(
            asbf8(af2[dt][kt]), bb, acc[dt][nt], 0, 0, 0);
    }

  // ---- epilogue 2: z -> Bt (dead after phase 1)
#pragma unroll
  for (int dt = 0; dt < 4; ++dt) {
    int dbase = d0 + dt * 16 + q * 4;
    float4 bi = *(const float4*)(bp + dbase);
    float bv[4] = {bi.x, bi.y, bi.z, bi.w};
#pragma unroll
    for (int nt = 0; nt < 2; ++nt) {
      int nl = nbw + nt * 16 + lm;
      ushort4 o;
      o.x = f2bf(fmaxf(acc[dt][nt][0] + bv[0], 0.f));
      o.y = f2bf(fmaxf(acc[dt][nt][1] + bv[1], 0.f));
      o.z = f2bf(fmaxf(acc[dt][nt][2] + bv[2], 0.f));
      o.w = f2bf(fmaxf(acc[dt][nt][3] + bv[3], 0.f));
      int chunk = dbase >> 3;
      int phys  = nl * 256 + ((chunk ^ (nl & 7)) << 4) + ((q & 1) << 3);
      *(ushort4*)(BtB + phys) = o;
    }
  }

  __syncthreads();   // barrier 3: Bt(z) complete

  // ---- coalesced z_t write from Bt
  {
    int nl = t >> 2;
    int gn = n0 + nl;
#pragma unroll
    for (int rep = 0; rep < 4; ++rep) {
      int g = (t & 3) + rep * 4;
      int phys = nl * 256 + ((g ^ (nl & 7)) << 4);
      uint4 v = *(const uint4*)(BtB + phys);
      if (gn < NODES)
        *(uint4*)((char*)z_t + (nb + (size_t)gn) * 256 + g * 16) = v;
    }
  }
}

// ---------------------------------------------------------------------------
// gmax_kernel: zm[b][n][128] = max_k z[b][idx[n,k]][128].  (unchanged)
// ---------------------------------------------------------------------------
__global__ __launch_bounds__(256) void gmax_kernel(
    const unsigned short* __restrict__ z_t, const int* __restrict__ e0,
    unsigned short* __restrict__ zm)
{
  const int bid = blockIdx.x;
  const int b   = bid & 7;
  const int n0  = (bid >> 3) * 64;
  const int t   = threadIdx.x;
  const int nl  = t >> 2, c = t & 3;
  const int gn  = n0 + nl;
  if (gn >= NODES) return;          // no barrier in this kernel: safe

  const int* ip = e0 + ((size_t)b * NODES + gn) * KNB;
  int4 iv0 = *(const int4*)(ip);
  int4 iv1 = *(const int4*)(ip + 4);
  int4 iv2 = *(const int4*)(ip + 8);
  int4 iv3 = *(const int4*)(ip + 12);
  int idx[16] = {iv0.x, iv0.y, iv0.z, iv0.w,
                 iv1.x, iv1.y, iv1.z, iv1.w,
                 iv2.x, iv2.y, iv2.z, iv2.w,
                 iv3.x, iv3.y, iv3.z, iv3.w};

  const char* Z = (const char*)(z_t + (size_t)b * NODES * CH) + c * 16;
  uint4 m[4];
#pragma unroll
  for (int cg = 0; cg < 4; ++cg) m[cg] = make_uint4(0u, 0u, 0u, 0u);

#pragma unroll
  for (int k = 0; k < KNB; ++k) {
    const char* p = Z + (size_t)idx[k] * (CH * 2);
#pragma unroll
    for (int cg = 0; cg < 4; ++cg)
      m[cg] = pkmax4(m[cg], *(const uint4*)(p + cg * 64));
  }

  char* O = (char*)(zm + ((size_t)b * NODES + gn) * CH) + c * 16;
#pragma unroll
  for (int cg = 0; cg < 4; ++cg)
    *(uint4*)(O + cg * 64) = m[cg];
}

// ---------------------------------------------------------------------------
// out_gemm (R1 version restored — best measured: 48.4 us).
// LDS-staged cat tile, 4 waves, grid 1256.
// ---------------------------------------------------------------------------
__global__ __launch_bounds__(256) void out_gemm(
    const unsigned short* __restrict__ h_t, const unsigned short* __restrict__ zm,
    const unsigned short* __restrict__ W2b, const float* __restrict__ b2,
    float* __restrict__ out)
{
  const int bid = blockIdx.x;
  const int b   = bid & 7;
  const int n0  = (bid >> 3) * 64;
  const int t   = threadIdx.x;
  const int lane = t & 63, w = t >> 6;
  const int lm = lane & 15, q = lane >> 4;

  __shared__ __align__(16) unsigned short cat[64 * 256];  // 32 KB, swizzled
  char* catB = (char*)cat;

  // ---- stage h (chunks 0-15) + zmax (chunks 16-31): 256B contiguous runs
#pragma unroll
  for (int rep = 0; rep < 8; ++rep) {
    int flat = t + rep * 256;           // 0..2047
    int nl = flat >> 5, chunk = flat & 31;
    int gn = n0 + nl;
    uint4 v = make_uint4(0u, 0u, 0u, 0u);
    if (gn < NODES) {
      const unsigned short* src = (chunk < 16)
        ? h_t + ((size_t)b * NODES + gn) * CH + chunk * 8
        : zm  + ((size_t)b * NODES + gn) * CH + (chunk - 16) * 8;
      v = *(const uint4*)src;
    }
    int phys = nl * 512 + ((chunk ^ (nl & 7)) << 4);
    *(uint4*)(catB + phys) = v;
  }
  __syncthreads();

  // ---- MFMA: wave w -> d in [64w, 64w+64), 64 nodes, K=256, W2 dbuf
  const int d0 = w * 64;
  f32x4 acc[4][4];
#pragma unroll
  for (int dt = 0; dt < 4; ++dt)
#pragma unroll
    for (int nt = 0; nt < 4; ++nt) acc[dt][nt] = (f32x4){0.f, 0.f, 0.f, 0.f};

  uint4 acur[4], anxt[4];
#pragma unroll
  for (int dt = 0; dt < 4; ++dt)
    acur[dt] = *(const uint4*)(W2b + (d0 + dt * 16 + lm) * CO + q * 8);

#pragma unroll
  for (int kt = 0; kt < 8; ++kt) {
    if (kt < 7) {
#pragma unroll
      for (int dt = 0; dt < 4; ++dt)
        anxt[dt] = *(const uint4*)(W2b + (d0 + dt * 16 + lm) * CO
                                   + (kt + 1) * 32 + q * 8);
    }
#pragma unroll
    for (int nt = 0; nt < 4; ++nt) {
      int nl = nt * 16 + lm;
      int chunk = kt * 4 + q;
      int phys = nl * 512 + ((chunk ^ (nl & 7)) << 4);
      bf16x8 bb = asbf8(*(const uint4*)(catB + phys));
#pragma unroll
      for (int dt = 0; dt < 4; ++dt)
        acc[dt][nt] = __builtin_amdgcn_mfma_f32_16x16x32_bf16(
            asbf8(acur[dt]), bb, acc[dt][nt], 0, 0, 0);
    }
#pragma unroll
    for (int dt = 0; dt < 4; ++dt) acur[dt] = anxt[dt];
  }

  // ---- epilogue: fp32 out [b][d][n]
#pragma unroll
  for (int dt = 0; dt < 4; ++dt) {
    int dbase = d0 + dt * 16 + q * 4;
    float4 bi = *(const float4*)(b2 + dbase);
    float bv[4] = {bi.x, bi.y, bi.z, bi.w};
#pragma unroll
    for (int nt = 0; nt < 4; ++nt) {
      int gn = n0 + nt * 16 + lm;
      if (gn < NODES) {
        float* op = out + ((size_t)(b * CO + dbase) * NODES) + gn;
#pragma unroll
        for (int r = 0; r < 4; ++r)
          op[(size_t)r * NODES] = fmaxf(acc[dt][nt][r] + bv[r], 0.f);
      }
    }
  }
}

// ---------------------------------------------------------------------------
// probe_store (DIAGNOSTIC): replays out_gemm's exact epilogue store pattern
// (grid 1256, 4 waves, 64 global_store_dword/thread/pass) into ws scratch,
// amplified 4x with slab rotation (defeats dead-store elim, same aggregate
// address pattern). Runs LAST -> zero interference with the real path.
// Read: dur/4 vs real epilogue share. ~45us/pass => write-pattern-bound;
// ~14us/pass => writes fine, stall is intra-kernel serialization.
// ---------------------------------------------------------------------------
__global__ __launch_bounds__(256) void probe_store(
    const float* __restrict__ b2, float* __restrict__ scratch)
{
  const int bid = blockIdx.x;
  const int n0  = (bid >> 3) * 64;
  const int t   = threadIdx.x;
  const int lane = t & 63, w = t >> 6;
  const int lm = lane & 15, q = lane >> 4;
  const int d0 = w * 64;

#pragma unroll
  for (int pass = 0; pass < 4; ++pass) {
    const int b = (bid + pass) & 7;     // rotate slab each pass
#pragma unroll
    for (int dt = 0; dt < 4; ++dt) {
      int dbase = d0 + dt * 16 + q * 4;
      float4 bi = *(const float4*)(b2 + dbase);
      float bv[4] = {bi.x, bi.y, bi.z, bi.w};
#pragma unroll
      for (int nt = 0; nt < 4; ++nt) {
        int gn = n0 + nt * 16 + lm;
        if (gn < NODES) {
          float* op = scratch + ((size_t)(b * CO + dbase) * NODES) + gn;
#pragma unroll
          for (int r = 0; r < 4; ++r)
            op[(size_t)r * NODES] = bv[r] + (float)(pass + gn);
        }
      }
    }
  }
}

// ---------------------------------------------------------------------------
extern "C" void kernel_launch(void* const* d_in, const int* in_sizes, int n_in,
                              void* d_out, int out_size, void* d_ws, size_t ws_size,
                              hipStream_t stream) {
  const float* x  = (const float*)d_in[0];
  const int*   ei = (const int*)d_in[1];   // (2,B,N,K); first half = targets
  const float* W1 = (const float*)d_in[2];
  const float* b1 = (const float*)d_in[3];
  const float* Wp = (const float*)d_in[4];
  const float* bp = (const float*)d_in[5];
  const float* W2 = (const float*)d_in[6];
  const float* b2 = (const float*)d_in[7];
  float* out = (float*)d_out;

  unsigned short* ws  = (unsigned short*)d_ws;
  unsigned short* h_t = ws;                                   // [B][N][128] bf16
  unsigned short* z_t = h_t + (size_t)BATCH * NODES * CH;     // [B][N][128] bf16
  unsigned short* W1b = z_t + (size_t)BATCH * NODES * CH;
  unsigned short* Wpb = W1b + CH * CH;
  unsigned short* W2b = Wpb + CH * CH;
  unsigned short* zm  = W2b + CO * 2 * CH;                    // [B][N][128] bf16
  unsigned short* scr = zm + (size_t)BATCH * NODES * CH;      // probe scratch

  prep<<<96, 256, 0, stream>>>(W1, Wp, W2, W1b, Wpb, W2b);

  const int NT = (NODES + 63) / 64;         // 157 tiles of 64 nodes
  fused_hz<<<dim3(NT, BATCH), 256, 0, stream>>>(W1b, b1, Wpb, bp, x, h_t, z_t);
  gmax_kernel<<<BATCH * NT, 256, 0, stream>>>(z_t, ei, zm);
  out_gemm<<<BATCH * NT, 256, 0, stream>>>(h_t, zm, W2b, b2, out);

  // diagnostic probe: only if workspace is large enough (ws re-poison fill
  // suggests ~320 MB; need 143.6 MB)
  size_t need = ((size_t)((char*)scr - (char*)d_ws))
              + (size_t)BATCH * CO * NODES * 4;
  if (ws_size >= need)
    probe_store<<<BATCH * NT, 256, 0, stream>>>(b2, (float*)scr);
}

// Round 6
// 198.970 us; speedup vs baseline: 1.3758x; 1.3758x over previous
//
#include <hip/hip_runtime.h>

#define NODES 10000
#define BATCH 8
#define CH    128
#define KNB   16
#define CO    256

typedef __bf16 bf16x8 __attribute__((ext_vector_type(8)));
typedef float  f32x4  __attribute__((ext_vector_type(4)));

__device__ __forceinline__ unsigned short f2bf(float f) {
  unsigned u = __float_as_uint(f);
  u = (u + 0x7FFFu + ((u >> 16) & 1u)) >> 16;   // RNE
  return (unsigned short)u;
}

// max of packed non-negative bf16 == packed u16 max (relu guarantees >=0)
__device__ __forceinline__ unsigned pkmax(unsigned a, unsigned b) {
  unsigned d;
  asm("v_pk_max_u16 %0, %1, %2" : "=v"(d) : "v"(a), "v"(b));
  return d;
}
__device__ __forceinline__ uint4 pkmax4(uint4 a, uint4 b) {
  a.x = pkmax(a.x, b.x); a.y = pkmax(a.y, b.y);
  a.z = pkmax(a.z, b.z); a.w = pkmax(a.w, b.w);
  return a;
}
__device__ __forceinline__ bf16x8 asbf8(uint4 u) {
  union { uint4 u; bf16x8 b; } c; c.u = u; return c.b;
}

// async global->LDS DMA, 16B per lane; LDS dst = base + lane*16 (linear)
__device__ __forceinline__ void gload_lds16(const void* g, void* l) {
  __builtin_amdgcn_global_load_lds(
      (const __attribute__((address_space(1))) unsigned int*)g,
      (__attribute__((address_space(3))) unsigned int*)l, 16, 0, 0);
}

// ---------------------------------------------------------------------------
// fp32 -> bf16 weight conversion (row-major [d][k] kept)
// ---------------------------------------------------------------------------
__global__ __launch_bounds__(256) void prep(
    const float* __restrict__ W1, const float* __restrict__ Wp,
    const float* __restrict__ W2,
    unsigned short* __restrict__ W1b, unsigned short* __restrict__ Wpb,
    unsigned short* __restrict__ W2b)
{
  int i = blockIdx.x * 256 + threadIdx.x;   // float4 index, 24576 total
  const float* src; unsigned short* dst; int off;
  if (i < 4096)      { src = W1; dst = W1b; off = i; }
  else if (i < 8192) { src = Wp; dst = Wpb; off = i - 4096; }
  else               { src = W2; dst = W2b; off = i - 8192; }
  float4 v = ((const float4*)src)[off];
  ushort4 o;
  o.x = f2bf(v.x); o.y = f2bf(v.y); o.z = f2bf(v.z); o.w = f2bf(v.w);
  ((ushort4*)dst)[off] = o;
}

// ---------------------------------------------------------------------------
// Fused: h = relu(W1 x + b1); z = relu(Wp h + bp), node-major bf16 [b][n][128].
// (v2, unchanged from R5: LDS-repacked coalesced global stores)
// ---------------------------------------------------------------------------
__global__ __launch_bounds__(256) void fused_hz(
    const unsigned short* __restrict__ W1b, const float* __restrict__ b1,
    const unsigned short* __restrict__ Wpb, const float* __restrict__ bp,
    const float* __restrict__ x,
    unsigned short* __restrict__ h_t, unsigned short* __restrict__ z_t)
{
  const int b  = blockIdx.y;
  const int n0 = blockIdx.x * 64;
  const int t  = threadIdx.x;
  const int lane = t & 63, w = t >> 6;
  const int lm = lane & 15, q = lane >> 4;
  const size_t nb = (size_t)b * NODES;

  __shared__ __align__(16) unsigned short Bt[64 * 128];   // x tile, 16 KB
  __shared__ __align__(16) unsigned short Ht[64 * 128];   // h tile, 16 KB
  char* BtB = (char*)Bt;
  char* HtB = (char*)Ht;

  // ---- stage x: fp32 [b][c][n] -> bf16 [n][c], XOR-swizzled 16B chunks
  {
    const float* X = x + (size_t)b * CH * NODES;
#pragma unroll
    for (int rep = 0; rep < 4; ++rep) {
      int flat = t + rep * 256;
      int c2 = flat >> 4, n4 = flat & 15;
      int c  = c2 * 2;
      int gn = n0 + n4 * 4;
      float4 a0 = make_float4(0.f,0.f,0.f,0.f), a1 = a0;
      if (gn < NODES) {
        a0 = *(const float4*)(X + (size_t)c * NODES + gn);
        a1 = *(const float4*)(X + (size_t)(c + 1) * NODES + gn);
      }
      float v0[4] = {a0.x, a0.y, a0.z, a0.w};
      float v1[4] = {a1.x, a1.y, a1.z, a1.w};
#pragma unroll
      for (int i = 0; i < 4; ++i) {
        int nn = n4 * 4 + i;
        unsigned pk = (unsigned)f2bf(v0[i]) | ((unsigned)f2bf(v1[i]) << 16);
        int phys = nn * 256 + (((c2 >> 2) ^ (nn & 7)) << 4) + ((c2 & 3) << 2);
        *(unsigned*)(BtB + phys) = pk;
      }
    }
  }

  const int d0  = (w & 1) * 64;      // d-half for this wave
  const int nbw = (w >> 1) * 32;     // node-pair base

  // W1 A-fragments (global, L2-hot)
  uint4 af[4][4];
#pragma unroll
  for (int dt = 0; dt < 4; ++dt)
#pragma unroll
    for (int kt = 0; kt < 4; ++kt)
      af[dt][kt] = *(const uint4*)(W1b + (d0 + dt*16 + lm) * CH + kt*32 + q*8);

  __syncthreads();   // barrier 1: Bt staged

  // ---- phase 1 MFMA: h-tile
  f32x4 acc[4][2];
#pragma unroll
  for (int dt = 0; dt < 4; ++dt)
#pragma unroll
    for (int nt = 0; nt < 2; ++nt) acc[dt][nt] = (f32x4){0.f,0.f,0.f,0.f};

#pragma unroll
  for (int kt = 0; kt < 4; ++kt)
#pragma unroll
    for (int nt = 0; nt < 2; ++nt) {
      int nl = nbw + nt * 16 + lm;
      int chunk = kt * 4 + q;
      int phys = nl * 256 + ((chunk ^ (nl & 7)) << 4);
      bf16x8 bb = asbf8(*(const uint4*)(BtB + phys));
#pragma unroll
      for (int dt = 0; dt < 4; ++dt)
        acc[dt][nt] = __builtin_amdgcn_mfma_f32_16x16x32_bf16(
            asbf8(af[dt][kt]), bb, acc[dt][nt], 0, 0, 0);
    }

  // Wp A-fragments for phase 2 (issue loads before the barrier)
  uint4 af2[4][4];
#pragma unroll
  for (int dt = 0; dt < 4; ++dt)
#pragma unroll
    for (int kt = 0; kt < 4; ++kt)
      af2[dt][kt] = *(const uint4*)(Wpb + (d0 + dt*16 + lm) * CH + kt*32 + q*8);

  // ---- epilogue 1: bias+relu+bf16 -> Ht LDS only (B-frag layout)
#pragma unroll
  for (int dt = 0; dt < 4; ++dt) {
    int dbase = d0 + dt * 16 + q * 4;
    float4 bi = *(const float4*)(b1 + dbase);
    float bv[4] = {bi.x, bi.y, bi.z, bi.w};
#pragma unroll
    for (int nt = 0; nt < 2; ++nt) {
      int nl = nbw + nt * 16 + lm;
      ushort4 o;
      o.x = f2bf(fmaxf(acc[dt][nt][0] + bv[0], 0.f));
      o.y = f2bf(fmaxf(acc[dt][nt][1] + bv[1], 0.f));
      o.z = f2bf(fmaxf(acc[dt][nt][2] + bv[2], 0.f));
      o.w = f2bf(fmaxf(acc[dt][nt][3] + bv[3], 0.f));
      int chunk = dbase >> 3;
      int phys  = nl * 256 + ((chunk ^ (nl & 7)) << 4) + ((q & 1) << 3);
      *(ushort4*)(HtB + phys) = o;
    }
  }

  __syncthreads();   // barrier 2: Ht complete

  // ---- coalesced h_t write: quad (nl = t>>2, g = t&3 + 4*rep) -> 64B/quad
  {
    int nl = t >> 2;
    int gn = n0 + nl;
#pragma unroll
    for (int rep = 0; rep < 4; ++rep) {
      int g = (t & 3) + rep * 4;
      int phys = nl * 256 + ((g ^ (nl & 7)) << 4);
      uint4 v = *(const uint4*)(HtB + phys);
      if (gn < NODES)
        *(uint4*)((char*)h_t + (nb + (size_t)gn) * 256 + g * 16) = v;
    }
  }

  // ---- phase 2 MFMA: z-tile from Ht
#pragma unroll
  for (int dt = 0; dt < 4; ++dt)
#pragma unroll
    for (int nt = 0; nt < 2; ++nt) acc[dt][nt] = (f32x4){0.f,0.f,0.f,0.f};

#pragma unroll
  for (int kt = 0; kt < 4; ++kt)
#pragma unroll
    for (int nt = 0; nt < 2; ++nt) {
      int nl = nbw + nt * 16 + lm;
      int chunk = kt * 4 + q;
      int phys = nl * 256 + ((chunk ^ (nl & 7)) << 4);
      bf16x8 bb = asbf8(*(const uint4*)(HtB + phys));
#pragma unroll
      for (int dt = 0; dt < 4; ++dt)
        acc[dt][nt] = __builtin_amdgcn_mfma_f32_16x16x32_bf16(
            asbf8(af2[dt][kt]), bb, acc[dt][nt], 0, 0, 0);
    }

  // ---- epilogue 2: z -> Bt (dead after phase 1)
#pragma unroll
  for (int dt = 0; dt < 4; ++dt) {
    int dbase = d0 + dt * 16 + q * 4;
    float4 bi = *(const float4*)(bp + dbase);
    float bv[4] = {bi.x, bi.y, bi.z, bi.w};
#pragma unroll
    for (int nt = 0; nt < 2; ++nt) {
      int nl = nbw + nt * 16 + lm;
      ushort4 o;
      o.x = f2bf(fmaxf(acc[dt][nt][0] + bv[0], 0.f));
      o.y = f2bf(fmaxf(acc[dt][nt][1] + bv[1], 0.f));
      o.z = f2bf(fmaxf(acc[dt][nt][2] + bv[2], 0.f));
      o.w = f2bf(fmaxf(acc[dt][nt][3] + bv[3], 0.f));
      int chunk = dbase >> 3;
      int phys  = nl * 256 + ((chunk ^ (nl & 7)) << 4) + ((q & 1) << 3);
      *(ushort4*)(BtB + phys) = o;
    }
  }

  __syncthreads();   // barrier 3: Bt(z) complete

  // ---- coalesced z_t write from Bt
  {
    int nl = t >> 2;
    int gn = n0 + nl;
#pragma unroll
    for (int rep = 0; rep < 4; ++rep) {
      int g = (t & 3) + rep * 4;
      int phys = nl * 256 + ((g ^ (nl & 7)) << 4);
      uint4 v = *(const uint4*)(BtB + phys);
      if (gn < NODES)
        *(uint4*)((char*)z_t + (nb + (size_t)gn) * 256 + g * 16) = v;
    }
  }
}

// ---------------------------------------------------------------------------
// gmax_kernel: zm[b][n][128] = max_k z[b][idx[n,k]][128].  (unchanged)
// ---------------------------------------------------------------------------
__global__ __launch_bounds__(256) void gmax_kernel(
    const unsigned short* __restrict__ z_t, const int* __restrict__ e0,
    unsigned short* __restrict__ zm)
{
  const int bid = blockIdx.x;
  const int b   = bid & 7;
  const int n0  = (bid >> 3) * 64;
  const int t   = threadIdx.x;
  const int nl  = t >> 2, c = t & 3;
  const int gn  = n0 + nl;
  if (gn >= NODES) return;          // no barrier in this kernel: safe

  const int* ip = e0 + ((size_t)b * NODES + gn) * KNB;
  int4 iv0 = *(const int4*)(ip);
  int4 iv1 = *(const int4*)(ip + 4);
  int4 iv2 = *(const int4*)(ip + 8);
  int4 iv3 = *(const int4*)(ip + 12);
  int idx[16] = {iv0.x, iv0.y, iv0.z, iv0.w,
                 iv1.x, iv1.y, iv1.z, iv1.w,
                 iv2.x, iv2.y, iv2.z, iv2.w,
                 iv3.x, iv3.y, iv3.z, iv3.w};

  const char* Z = (const char*)(z_t + (size_t)b * NODES * CH) + c * 16;
  uint4 m[4];
#pragma unroll
  for (int cg = 0; cg < 4; ++cg) m[cg] = make_uint4(0u, 0u, 0u, 0u);

#pragma unroll
  for (int k = 0; k < KNB; ++k) {
    const char* p = Z + (size_t)idx[k] * (CH * 2);
#pragma unroll
    for (int cg = 0; cg < 4; ++cg)
      m[cg] = pkmax4(m[cg], *(const uint4*)(p + cg * 64));
  }

  char* O = (char*)(zm + ((size_t)b * NODES + gn) * CH) + c * 16;
#pragma unroll
  for (int cg = 0; cg < 4; ++cg)
    *(uint4*)(O + cg * 64) = m[cg];
}

// ---------------------------------------------------------------------------
// out_gemm v5: 2-3 tiles per block, double-buffered async-DMA pipeline.
//  - staging via global_load_lds w=16: linear LDS dst, swizzle moved to the
//    per-lane global SOURCE address (XOR involution) -> zero ds_write
//    conflicts, zero staging VGPRs
//  - W2 A-frags af[8][4] preloaded ONCE (tile-invariant, no loads in loop)
//  - schedule: stage(next) -> MFMA(cur) -> vmcnt(0)+barrier -> stores, so
//    each tile's store burst drains under the next tile's MFMA phase
//  - grid 512 = 8 batches x 64 groups; 64KB LDS -> exactly 2 blocks/CU,
//    all resident; block g owns tiles {g, g+64, g+128<157}
// ---------------------------------------------------------------------------
__device__ __forceinline__ void og_stage(
    unsigned short* buf, const unsigned short* __restrict__ h_t,
    const unsigned short* __restrict__ zm, size_t nb, int n0, int w, int lane)
{
#pragma unroll
  for (int rep = 0; rep < 8; ++rep) {
    const int row0 = w * 2 + rep * 8;            // wave-uniform row pair
    const int nl = row0 + (lane >> 5);
    const int l  = (lane & 31) ^ (nl & 7);       // pre-swizzled source chunk
    int gn = n0 + nl; if (gn > NODES - 1) gn = NODES - 1;   // clamp, masked later
    const unsigned short* src = (l < 16)
        ? h_t + (nb + (size_t)gn) * CH + l * 8
        : zm  + (nb + (size_t)gn) * CH + (l - 16) * 8;
    gload_lds16(src, (char*)buf + row0 * 512);
  }
  __builtin_amdgcn_sched_barrier(0);             // pin DMA issue before compute
}

__device__ __forceinline__ void og_mfma(
    f32x4 (&acc)[4][4], const unsigned short* buf,
    const uint4 (&af)[8][4], int lm, int q)
{
  const char* catB = (const char*)buf;
#pragma unroll
  for (int dt = 0; dt < 4; ++dt)
#pragma unroll
    for (int nt = 0; nt < 4; ++nt) acc[dt][nt] = (f32x4){0.f, 0.f, 0.f, 0.f};
#pragma unroll
  for (int kt = 0; kt < 8; ++kt)
#pragma unroll
    for (int nt = 0; nt < 4; ++nt) {
      int nl = nt * 16 + lm;
      int chunk = kt * 4 + q;
      int phys = nl * 512 + ((chunk ^ (nl & 7)) << 4);
      bf16x8 bb = asbf8(*(const uint4*)(catB + phys));
#pragma unroll
      for (int dt = 0; dt < 4; ++dt)
        acc[dt][nt] = __builtin_amdgcn_mfma_f32_16x16x32_bf16(
            asbf8(af[kt][dt]), bb, acc[dt][nt], 0, 0, 0);
    }
}

__device__ __forceinline__ void og_epi(
    const f32x4 (&acc)[4][4], const float* __restrict__ b2,
    float* __restrict__ out, int b, int n0, int w, int lm, int q)
{
  const int d0 = w * 64;
#pragma unroll
  for (int dt = 0; dt < 4; ++dt) {
    int dbase = d0 + dt * 16 + q * 4;
    float4 bi = *(const float4*)(b2 + dbase);
    float bv[4] = {bi.x, bi.y, bi.z, bi.w};
#pragma unroll
    for (int nt = 0; nt < 4; ++nt) {
      int gn = n0 + nt * 16 + lm;
      if (gn < NODES) {
        float* op = out + ((size_t)(b * CO + dbase) * NODES) + gn;
#pragma unroll
        for (int r = 0; r < 4; ++r)
          op[(size_t)r * NODES] = fmaxf(acc[dt][nt][r] + bv[r], 0.f);
      }
    }
  }
}

__global__ __launch_bounds__(256) void out_gemm(
    const unsigned short* __restrict__ h_t, const unsigned short* __restrict__ zm,
    const unsigned short* __restrict__ W2b, const float* __restrict__ b2,
    float* __restrict__ out)
{
  const int bid = blockIdx.x;
  const int b   = bid & 7;
  const int g   = bid >> 3;                // 0..63
  const int t   = threadIdx.x;
  const int lane = t & 63, w = t >> 6;
  const int lm = lane & 15, q = lane >> 4;
  const size_t nb = (size_t)b * NODES;

  __shared__ __align__(16) unsigned short bufA[64 * 256];   // 32 KB
  __shared__ __align__(16) unsigned short bufB[64 * 256];   // 32 KB

  // W2 A-fragments, tile-invariant: af[kt][dt]
  const int d0 = w * 64;
  uint4 af[8][4];
#pragma unroll
  for (int kt = 0; kt < 8; ++kt)
#pragma unroll
    for (int dt = 0; dt < 4; ++dt)
      af[kt][dt] = *(const uint4*)(W2b + (d0 + dt*16 + lm) * CO + kt*32 + q*8);

  const int n0_0 = g * 64;
  const int n0_1 = (g + 64) * 64;
  const int n0_2 = (g + 128) * 64;
  const bool has2 = (g + 128) < 157;

  f32x4 acc[4][4];

  // prologue: stage tile0
  og_stage(bufA, h_t, zm, nb, n0_0, w, lane);
  asm volatile("s_waitcnt vmcnt(0)" ::: "memory");
  __builtin_amdgcn_sched_barrier(0);
  __builtin_amdgcn_s_barrier();

  // iter 0: stage t1 || compute t0; stores(t0) drain under iter-1 compute
  og_stage(bufB, h_t, zm, nb, n0_1, w, lane);
  og_mfma(acc, bufA, af, lm, q);
  asm volatile("s_waitcnt vmcnt(0)" ::: "memory");
  __builtin_amdgcn_sched_barrier(0);
  __builtin_amdgcn_s_barrier();
  og_epi(acc, b2, out, b, n0_0, w, lm, q);

  if (has2) {
    // iter 1: stage t2 || compute t1
    og_stage(bufA, h_t, zm, nb, n0_2, w, lane);
    og_mfma(acc, bufB, af, lm, q);
    asm volatile("s_waitcnt vmcnt(0)" ::: "memory");
    __builtin_amdgcn_sched_barrier(0);
    __builtin_amdgcn_s_barrier();
    og_epi(acc, b2, out, b, n0_1, w, lm, q);
    // iter 2: compute t2
    og_mfma(acc, bufA, af, lm, q);
    og_epi(acc, b2, out, b, n0_2, w, lm, q);
  } else {
    og_mfma(acc, bufB, af, lm, q);
    og_epi(acc, b2, out, b, n0_1, w, lm, q);
  }
}

// ---------------------------------------------------------------------------
extern "C" void kernel_launch(void* const* d_in, const int* in_sizes, int n_in,
                              void* d_out, int out_size, void* d_ws, size_t ws_size,
                              hipStream_t stream) {
  const float* x  = (const float*)d_in[0];
  const int*   ei = (const int*)d_in[1];   // (2,B,N,K); first half = targets
  const float* W1 = (const float*)d_in[2];
  const float* b1 = (const float*)d_in[3];
  const float* Wp = (const float*)d_in[4];
  const float* bp = (const float*)d_in[5];
  const float* W2 = (const float*)d_in[6];
  const float* b2 = (const float*)d_in[7];
  float* out = (float*)d_out;

  unsigned short* ws  = (unsigned short*)d_ws;
  unsigned short* h_t = ws;                                   // [B][N][128] bf16
  unsigned short* z_t = h_t + (size_t)BATCH * NODES * CH;     // [B][N][128] bf16
  unsigned short* W1b = z_t + (size_t)BATCH * NODES * CH;
  unsigned short* Wpb = W1b + CH * CH;
  unsigned short* W2b = Wpb + CH * CH;
  unsigned short* zm  = W2b + CO * 2 * CH;                    // [B][N][128] bf16

  prep<<<96, 256, 0, stream>>>(W1, Wp, W2, W1b, Wpb, W2b);

  const int NT = (NODES + 63) / 64;         // 157 tiles of 64 nodes
  fused_hz<<<dim3(NT, BATCH), 256, 0, stream>>>(W1b, b1, Wpb, bp, x, h_t, z_t);
  gmax_kernel<<<BATCH * NT, 256, 0, stream>>>(z_t, ei, zm);
  out_gemm<<<512, 256, 0, stream>>>(h_t, zm, W2b, b2, out);
}

// Round 7
// 194.777 us; speedup vs baseline: 1.4054x; 1.0215x over previous
//
#include <hip/hip_runtime.h>

#define NODES 10000
#define BATCH 8
#define CH    128
#define KNB   16
#define CO    256

typedef __bf16 bf16x8 __attribute__((ext_vector_type(8)));
typedef float  f32x4  __attribute__((ext_vector_type(4)));

__device__ __forceinline__ unsigned short f2bf(float f) {
  unsigned u = __float_as_uint(f);
  u = (u + 0x7FFFu + ((u >> 16) & 1u)) >> 16;   // RNE
  return (unsigned short)u;
}

// max of packed non-negative bf16 == packed u16 max (relu guarantees >=0)
__device__ __forceinline__ unsigned pkmax(unsigned a, unsigned b) {
  unsigned d;
  asm("v_pk_max_u16 %0, %1, %2" : "=v"(d) : "v"(a), "v"(b));
  return d;
}
__device__ __forceinline__ uint4 pkmax4(uint4 a, uint4 b) {
  a.x = pkmax(a.x, b.x); a.y = pkmax(a.y, b.y);
  a.z = pkmax(a.z, b.z); a.w = pkmax(a.w, b.w);
  return a;
}
__device__ __forceinline__ bf16x8 asbf8(uint4 u) {
  union { uint4 u; bf16x8 b; } c; c.u = u; return c.b;
}

// async global->LDS DMA, 16B per lane; LDS dst = base + lane*16 (linear)
__device__ __forceinline__ void gload_lds16(const void* g, void* l) {
  __builtin_amdgcn_global_load_lds(
      (const __attribute__((address_space(1))) unsigned int*)g,
      (__attribute__((address_space(3))) unsigned int*)l, 16, 0, 0);
}

// ---------------------------------------------------------------------------
// fp32 -> bf16 weight conversion (row-major [d][k] kept)
// ---------------------------------------------------------------------------
__global__ __launch_bounds__(256) void prep(
    const float* __restrict__ W1, const float* __restrict__ Wp,
    const float* __restrict__ W2,
    unsigned short* __restrict__ W1b, unsigned short* __restrict__ Wpb,
    unsigned short* __restrict__ W2b)
{
  int i = blockIdx.x * 256 + threadIdx.x;   // float4 index, 24576 total
  const float* src; unsigned short* dst; int off;
  if (i < 4096)      { src = W1; dst = W1b; off = i; }
  else if (i < 8192) { src = Wp; dst = Wpb; off = i - 4096; }
  else               { src = W2; dst = W2b; off = i - 8192; }
  float4 v = ((const float4*)src)[off];
  ushort4 o;
  o.x = f2bf(v.x); o.y = f2bf(v.y); o.z = f2bf(v.z); o.w = f2bf(v.w);
  ((ushort4*)dst)[off] = o;
}

// ---------------------------------------------------------------------------
// prep_x: x fp32 [b][c][n] -> x_t bf16 [b][n][128] (node-major, plain layout,
// same as h_t/z_t). Streaming transpose via 16KB LDS tile; coalesced 64B-per-
// quad writeback. Hoisted out of fused_hz so fused_hz can DMA-stage.
// ---------------------------------------------------------------------------
__global__ __launch_bounds__(256) void prep_x(
    const float* __restrict__ x, unsigned short* __restrict__ x_t)
{
  const int b  = blockIdx.y;
  const int n0 = blockIdx.x * 64;
  const int t  = threadIdx.x;
  const size_t nb = (size_t)b * NODES;

  __shared__ __align__(16) unsigned short Bt[64 * 128];   // 16 KB
  char* BtB = (char*)Bt;

  const float* X = x + (size_t)b * CH * NODES;
#pragma unroll
  for (int rep = 0; rep < 4; ++rep) {
    int flat = t + rep * 256;
    int c2 = flat >> 4, n4 = flat & 15;
    int c  = c2 * 2;
    int gn = n0 + n4 * 4;
    float4 a0 = make_float4(0.f,0.f,0.f,0.f), a1 = a0;
    if (gn < NODES) {
      a0 = *(const float4*)(X + (size_t)c * NODES + gn);
      a1 = *(const float4*)(X + (size_t)(c + 1) * NODES + gn);
    }
    float v0[4] = {a0.x, a0.y, a0.z, a0.w};
    float v1[4] = {a1.x, a1.y, a1.z, a1.w};
#pragma unroll
    for (int i = 0; i < 4; ++i) {
      int nn = n4 * 4 + i;
      unsigned pk = (unsigned)f2bf(v0[i]) | ((unsigned)f2bf(v1[i]) << 16);
      int phys = nn * 256 + (((c2 >> 2) ^ (nn & 7)) << 4) + ((c2 & 3) << 2);
      *(unsigned*)(BtB + phys) = pk;
    }
  }
  __syncthreads();

  // coalesced writeback: quad per node, logical chunk order
  {
    int nl = t >> 2;
    int gn = n0 + nl;
#pragma unroll
    for (int rep = 0; rep < 4; ++rep) {
      int g = (t & 3) + rep * 4;
      int phys = nl * 256 + ((g ^ (nl & 7)) << 4);
      uint4 v = *(const uint4*)(BtB + phys);
      if (gn < NODES)
        *(uint4*)((char*)x_t + (nb + (size_t)gn) * 256 + g * 16) = v;
    }
  }
}

// ---------------------------------------------------------------------------
// fused_hz v3: out_gemm-v5-style pipeline. 2-3 tiles/block (grid 512), DMA
// staging from node-major x_t (swizzle pre-applied to SOURCE address), W1+Wp
// fragments preloaded once, 64KB LDS (2 blocks/CU). Per tile:
//   stage(next) || MFMA1 -> Ht -> barrier -> h-store || MFMA2 -> Zt
//   -> barrier -> z-store -> vmcnt(0)+barrier.
// ---------------------------------------------------------------------------
__device__ __forceinline__ void hz_stage(
    unsigned short* buf, const unsigned short* __restrict__ x_t,
    size_t nb, int n0, int w, int lane)
{
#pragma unroll
  for (int rep = 0; rep < 4; ++rep) {
    const int row0 = w * 16 + rep * 4;          // wave-uniform base row
    const int nl = row0 + (lane >> 4);          // 4 rows per issue
    const int c  = lane & 15;                   // physical chunk
    const int l  = c ^ (nl & 7);                // logical chunk (involution)
    int gn = n0 + nl; if (gn > NODES - 1) gn = NODES - 1;   // clamp, masked later
    const unsigned short* src = x_t + (nb + (size_t)gn) * CH + l * 8;
    gload_lds16(src, (char*)buf + row0 * 256);
  }
  __builtin_amdgcn_sched_barrier(0);
}

__device__ __forceinline__ void hz_compute(
    const unsigned short* buf, unsigned short* Ht, unsigned short* Zt,
    const uint4 (&af)[4][4], const uint4 (&af2)[4][4],
    const float* __restrict__ b1, const float* __restrict__ bp,
    unsigned short* __restrict__ h_t, unsigned short* __restrict__ z_t,
    size_t nb, int n0, int t, int w, int lm, int q)
{
  const char* BtB = (const char*)buf;
  char* HtB = (char*)Ht;
  char* ZtB = (char*)Zt;
  const int d0  = (w & 1) * 64;
  const int nbw = (w >> 1) * 32;

  // ---- phase 1 MFMA: h-tile
  f32x4 acc[4][2];
#pragma unroll
  for (int dt = 0; dt < 4; ++dt)
#pragma unroll
    for (int nt = 0; nt < 2; ++nt) acc[dt][nt] = (f32x4){0.f,0.f,0.f,0.f};

#pragma unroll
  for (int kt = 0; kt < 4; ++kt)
#pragma unroll
    for (int nt = 0; nt < 2; ++nt) {
      int nl = nbw + nt * 16 + lm;
      int chunk = kt * 4 + q;
      int phys = nl * 256 + ((chunk ^ (nl & 7)) << 4);
      bf16x8 bb = asbf8(*(const uint4*)(BtB + phys));
#pragma unroll
      for (int dt = 0; dt < 4; ++dt)
        acc[dt][nt] = __builtin_amdgcn_mfma_f32_16x16x32_bf16(
            asbf8(af[dt][kt]), bb, acc[dt][nt], 0, 0, 0);
    }

  // ---- epilogue 1: bias+relu+bf16 -> Ht (B-frag layout)
#pragma unroll
  for (int dt = 0; dt < 4; ++dt) {
    int dbase = d0 + dt * 16 + q * 4;
    float4 bi = *(const float4*)(b1 + dbase);
    float bv[4] = {bi.x, bi.y, bi.z, bi.w};
#pragma unroll
    for (int nt = 0; nt < 2; ++nt) {
      int nl = nbw + nt * 16 + lm;
      ushort4 o;
      o.x = f2bf(fmaxf(acc[dt][nt][0] + bv[0], 0.f));
      o.y = f2bf(fmaxf(acc[dt][nt][1] + bv[1], 0.f));
      o.z = f2bf(fmaxf(acc[dt][nt][2] + bv[2], 0.f));
      o.w = f2bf(fmaxf(acc[dt][nt][3] + bv[3], 0.f));
      int chunk = dbase >> 3;
      int phys  = nl * 256 + ((chunk ^ (nl & 7)) << 4) + ((q & 1) << 3);
      *(ushort4*)(HtB + phys) = o;
    }
  }

  __syncthreads();   // Ht complete

  // ---- coalesced h_t store (drains under MFMA2)
  {
    int nl = t >> 2;
    int gn = n0 + nl;
#pragma unroll
    for (int rep = 0; rep < 4; ++rep) {
      int g = (t & 3) + rep * 4;
      int phys = nl * 256 + ((g ^ (nl & 7)) << 4);
      uint4 v = *(const uint4*)(HtB + phys);
      if (gn < NODES)
        *(uint4*)((char*)h_t + (nb + (size_t)gn) * 256 + g * 16) = v;
    }
  }

  // ---- phase 2 MFMA: z-tile from Ht
#pragma unroll
  for (int dt = 0; dt < 4; ++dt)
#pragma unroll
    for (int nt = 0; nt < 2; ++nt) acc[dt][nt] = (f32x4){0.f,0.f,0.f,0.f};

#pragma unroll
  for (int kt = 0; kt < 4; ++kt)
#pragma unroll
    for (int nt = 0; nt < 2; ++nt) {
      int nl = nbw + nt * 16 + lm;
      int chunk = kt * 4 + q;
      int phys = nl * 256 + ((chunk ^ (nl & 7)) << 4);
      bf16x8 bb = asbf8(*(const uint4*)(HtB + phys));
#pragma unroll
      for (int dt = 0; dt < 4; ++dt)
        acc[dt][nt] = __builtin_amdgcn_mfma_f32_16x16x32_bf16(
            asbf8(af2[dt][kt]), bb, acc[dt][nt], 0, 0, 0);
    }

  // ---- epilogue 2: z -> Zt (B-frag layout)
#pragma unroll
  for (int dt = 0; dt < 4; ++dt) {
    int dbase = d0 + dt * 16 + q * 4;
    float4 bi = *(const float4*)(bp + dbase);
    float bv[4] = {bi.x, bi.y, bi.z, bi.w};
#pragma unroll
    for (int nt = 0; nt < 2; ++nt) {
      int nl = nbw + nt * 16 + lm;
      ushort4 o;
      o.x = f2bf(fmaxf(acc[dt][nt][0] + bv[0], 0.f));
      o.y = f2bf(fmaxf(acc[dt][nt][1] + bv[1], 0.f));
      o.z = f2bf(fmaxf(acc[dt][nt][2] + bv[2], 0.f));
      o.w = f2bf(fmaxf(acc[dt][nt][3] + bv[3], 0.f));
      int chunk = dbase >> 3;
      int phys  = nl * 256 + ((chunk ^ (nl & 7)) << 4) + ((q & 1) << 3);
      *(ushort4*)(ZtB + phys) = o;
    }
  }

  __syncthreads();   // Zt complete

  // ---- coalesced z_t store
  {
    int nl = t >> 2;
    int gn = n0 + nl;
#pragma unroll
    for (int rep = 0; rep < 4; ++rep) {
      int g = (t & 3) + rep * 4;
      int phys = nl * 256 + ((g ^ (nl & 7)) << 4);
      uint4 v = *(const uint4*)(ZtB + phys);
      if (gn < NODES)
        *(uint4*)((char*)z_t + (nb + (size_t)gn) * 256 + g * 16) = v;
    }
  }
}

__global__ __launch_bounds__(256) void fused_hz(
    const unsigned short* __restrict__ W1b, const float* __restrict__ b1,
    const unsigned short* __restrict__ Wpb, const float* __restrict__ bp,
    const unsigned short* __restrict__ x_t,
    unsigned short* __restrict__ h_t, unsigned short* __restrict__ z_t)
{
  const int bid = blockIdx.x;
  const int b   = bid & 7;
  const int g   = bid >> 3;                // 0..63
  const int t   = threadIdx.x;
  const int lane = t & 63, w = t >> 6;
  const int lm = lane & 15, q = lane >> 4;
  const size_t nb = (size_t)b * NODES;

  __shared__ __align__(16) unsigned short bufA[64 * 128];   // 16 KB
  __shared__ __align__(16) unsigned short bufB[64 * 128];   // 16 KB
  __shared__ __align__(16) unsigned short Ht[64 * 128];     // 16 KB
  __shared__ __align__(16) unsigned short Zt[64 * 128];     // 16 KB

  const int d0 = (w & 1) * 64;

  // W1 + Wp A-fragments, tile-invariant (preload once)
  uint4 af[4][4], af2[4][4];
#pragma unroll
  for (int dt = 0; dt < 4; ++dt)
#pragma unroll
    for (int kt = 0; kt < 4; ++kt) {
      af[dt][kt]  = *(const uint4*)(W1b + (d0 + dt*16 + lm) * CH + kt*32 + q*8);
      af2[dt][kt] = *(const uint4*)(Wpb + (d0 + dt*16 + lm) * CH + kt*32 + q*8);
    }

  const int n0_0 = g * 64;
  const int n0_1 = (g + 64) * 64;
  const int n0_2 = (g + 128) * 64;
  const bool has2 = (g + 128) < 157;

  // prologue: stage tile0
  hz_stage(bufA, x_t, nb, n0_0, w, lane);
  asm volatile("s_waitcnt vmcnt(0)" ::: "memory");
  __builtin_amdgcn_sched_barrier(0);
  __builtin_amdgcn_s_barrier();

  // iter 0
  hz_stage(bufB, x_t, nb, n0_1, w, lane);
  hz_compute(bufA, Ht, Zt, af, af2, b1, bp, h_t, z_t, nb, n0_0, t, w, lm, q);
  asm volatile("s_waitcnt vmcnt(0)" ::: "memory");
  __builtin_amdgcn_sched_barrier(0);
  __builtin_amdgcn_s_barrier();

  if (has2) {
    hz_stage(bufA, x_t, nb, n0_2, w, lane);
    hz_compute(bufB, Ht, Zt, af, af2, b1, bp, h_t, z_t, nb, n0_1, t, w, lm, q);
    asm volatile("s_waitcnt vmcnt(0)" ::: "memory");
    __builtin_amdgcn_sched_barrier(0);
    __builtin_amdgcn_s_barrier();
    hz_compute(bufA, Ht, Zt, af, af2, b1, bp, h_t, z_t, nb, n0_2, t, w, lm, q);
  } else {
    hz_compute(bufB, Ht, Zt, af, af2, b1, bp, h_t, z_t, nb, n0_1, t, w, lm, q);
  }
}

// ---------------------------------------------------------------------------
// gmax_kernel: zm[b][n][128] = max_k z[b][idx[n,k]][128].  (unchanged)
// ---------------------------------------------------------------------------
__global__ __launch_bounds__(256) void gmax_kernel(
    const unsigned short* __restrict__ z_t, const int* __restrict__ e0,
    unsigned short* __restrict__ zm)
{
  const int bid = blockIdx.x;
  const int b   = bid & 7;
  const int n0  = (bid >> 3) * 64;
  const int t   = threadIdx.x;
  const int nl  = t >> 2, c = t & 3;
  const int gn  = n0 + nl;
  if (gn >= NODES) return;          // no barrier in this kernel: safe

  const int* ip = e0 + ((size_t)b * NODES + gn) * KNB;
  int4 iv0 = *(const int4*)(ip);
  int4 iv1 = *(const int4*)(ip + 4);
  int4 iv2 = *(const int4*)(ip + 8);
  int4 iv3 = *(const int4*)(ip + 12);
  int idx[16] = {iv0.x, iv0.y, iv0.z, iv0.w,
                 iv1.x, iv1.y, iv1.z, iv1.w,
                 iv2.x, iv2.y, iv2.z, iv2.w,
                 iv3.x, iv3.y, iv3.z, iv3.w};

  const char* Z = (const char*)(z_t + (size_t)b * NODES * CH) + c * 16;
  uint4 m[4];
#pragma unroll
  for (int cg = 0; cg < 4; ++cg) m[cg] = make_uint4(0u, 0u, 0u, 0u);

#pragma unroll
  for (int k = 0; k < KNB; ++k) {
    const char* p = Z + (size_t)idx[k] * (CH * 2);
#pragma unroll
    for (int cg = 0; cg < 4; ++cg)
      m[cg] = pkmax4(m[cg], *(const uint4*)(p + cg * 64));
  }

  char* O = (char*)(zm + ((size_t)b * NODES + gn) * CH) + c * 16;
#pragma unroll
  for (int cg = 0; cg < 4; ++cg)
    *(uint4*)(O + cg * 64) = m[cg];
}

// ---------------------------------------------------------------------------
// out_gemm v5 (unchanged from R6 — measured ~30 us).
// ---------------------------------------------------------------------------
__device__ __forceinline__ void og_stage(
    unsigned short* buf, const unsigned short* __restrict__ h_t,
    const unsigned short* __restrict__ zm, size_t nb, int n0, int w, int lane)
{
#pragma unroll
  for (int rep = 0; rep < 8; ++rep) {
    const int row0 = w * 2 + rep * 8;            // wave-uniform row pair
    const int nl = row0 + (lane >> 5);
    const int l  = (lane & 31) ^ (nl & 7);       // pre-swizzled source chunk
    int gn = n0 + nl; if (gn > NODES - 1) gn = NODES - 1;   // clamp, masked later
    const unsigned short* src = (l < 16)
        ? h_t + (nb + (size_t)gn) * CH + l * 8
        : zm  + (nb + (size_t)gn) * CH + (l - 16) * 8;
    gload_lds16(src, (char*)buf + row0 * 512);
  }
  __builtin_amdgcn_sched_barrier(0);             // pin DMA issue before compute
}

__device__ __forceinline__ void og_mfma(
    f32x4 (&acc)[4][4], const unsigned short* buf,
    const uint4 (&af)[8][4], int lm, int q)
{
  const char* catB = (const char*)buf;
#pragma unroll
  for (int dt = 0; dt < 4; ++dt)
#pragma unroll
    for (int nt = 0; nt < 4; ++nt) acc[dt][nt] = (f32x4){0.f, 0.f, 0.f, 0.f};
#pragma unroll
  for (int kt = 0; kt < 8; ++kt)
#pragma unroll
    for (int nt = 0; nt < 4; ++nt) {
      int nl = nt * 16 + lm;
      int chunk = kt * 4 + q;
      int phys = nl * 512 + ((chunk ^ (nl & 7)) << 4);
      bf16x8 bb = asbf8(*(const uint4*)(catB + phys));
#pragma unroll
      for (int dt = 0; dt < 4; ++dt)
        acc[dt][nt] = __builtin_amdgcn_mfma_f32_16x16x32_bf16(
            asbf8(af[kt][dt]), bb, acc[dt][nt], 0, 0, 0);
    }
}

__device__ __forceinline__ void og_epi(
    const f32x4 (&acc)[4][4], const float* __restrict__ b2,
    float* __restrict__ out, int b, int n0, int w, int lm, int q)
{
  const int d0 = w * 64;
#pragma unroll
  for (int dt = 0; dt < 4; ++dt) {
    int dbase = d0 + dt * 16 + q * 4;
    float4 bi = *(const float4*)(b2 + dbase);
    float bv[4] = {bi.x, bi.y, bi.z, bi.w};
#pragma unroll
    for (int nt = 0; nt < 4; ++nt) {
      int gn = n0 + nt * 16 + lm;
      if (gn < NODES) {
        float* op = out + ((size_t)(b * CO + dbase) * NODES) + gn;
#pragma unroll
        for (int r = 0; r < 4; ++r)
          op[(size_t)r * NODES] = fmaxf(acc[dt][nt][r] + bv[r], 0.f);
      }
    }
  }
}

__global__ __launch_bounds__(256) void out_gemm(
    const unsigned short* __restrict__ h_t, const unsigned short* __restrict__ zm,
    const unsigned short* __restrict__ W2b, const float* __restrict__ b2,
    float* __restrict__ out)
{
  const int bid = blockIdx.x;
  const int b   = bid & 7;
  const int g   = bid >> 3;                // 0..63
  const int t   = threadIdx.x;
  const int lane = t & 63, w = t >> 6;
  const int lm = lane & 15, q = lane >> 4;
  const size_t nb = (size_t)b * NODES;

  __shared__ __align__(16) unsigned short bufA[64 * 256];   // 32 KB
  __shared__ __align__(16) unsigned short bufB[64 * 256];   // 32 KB

  // W2 A-fragments, tile-invariant: af[kt][dt]
  const int d0 = w * 64;
  uint4 af[8][4];
#pragma unroll
  for (int kt = 0; kt < 8; ++kt)
#pragma unroll
    for (int dt = 0; dt < 4; ++dt)
      af[kt][dt] = *(const uint4*)(W2b + (d0 + dt*16 + lm) * CO + kt*32 + q*8);

  const int n0_0 = g * 64;
  const int n0_1 = (g + 64) * 64;
  const int n0_2 = (g + 128) * 64;
  const bool has2 = (g + 128) < 157;

  f32x4 acc[4][4];

  // prologue: stage tile0
  og_stage(bufA, h_t, zm, nb, n0_0, w, lane);
  asm volatile("s_waitcnt vmcnt(0)" ::: "memory");
  __builtin_amdgcn_sched_barrier(0);
  __builtin_amdgcn_s_barrier();

  // iter 0: stage t1 || compute t0; stores(t0) drain under iter-1 compute
  og_stage(bufB, h_t, zm, nb, n0_1, w, lane);
  og_mfma(acc, bufA, af, lm, q);
  asm volatile("s_waitcnt vmcnt(0)" ::: "memory");
  __builtin_amdgcn_sched_barrier(0);
  __builtin_amdgcn_s_barrier();
  og_epi(acc, b2, out, b, n0_0, w, lm, q);

  if (has2) {
    // iter 1: stage t2 || compute t1
    og_stage(bufA, h_t, zm, nb, n0_2, w, lane);
    og_mfma(acc, bufB, af, lm, q);
    asm volatile("s_waitcnt vmcnt(0)" ::: "memory");
    __builtin_amdgcn_sched_barrier(0);
    __builtin_amdgcn_s_barrier();
    og_epi(acc, b2, out, b, n0_1, w, lm, q);
    // iter 2: compute t2
    og_mfma(acc, bufA, af, lm, q);
    og_epi(acc, b2, out, b, n0_2, w, lm, q);
  } else {
    og_mfma(acc, bufB, af, lm, q);
    og_epi(acc, b2, out, b, n0_1, w, lm, q);
  }
}

// ---------------------------------------------------------------------------
extern "C" void kernel_launch(void* const* d_in, const int* in_sizes, int n_in,
                              void* d_out, int out_size, void* d_ws, size_t ws_size,
                              hipStream_t stream) {
  const float* x  = (const float*)d_in[0];
  const int*   ei = (const int*)d_in[1];   // (2,B,N,K); first half = targets
  const float* W1 = (const float*)d_in[2];
  const float* b1 = (const float*)d_in[3];
  const float* Wp = (const float*)d_in[4];
  const float* bp = (const float*)d_in[5];
  const float* W2 = (const float*)d_in[6];
  const float* b2 = (const float*)d_in[7];
  float* out = (float*)d_out;

  unsigned short* ws  = (unsigned short*)d_ws;
  unsigned short* h_t = ws;                                   // [B][N][128] bf16
  unsigned short* z_t = h_t + (size_t)BATCH * NODES * CH;     // [B][N][128] bf16
  unsigned short* W1b = z_t + (size_t)BATCH * NODES * CH;
  unsigned short* Wpb = W1b + CH * CH;
  unsigned short* W2b = Wpb + CH * CH;
  unsigned short* zm  = W2b + CO * 2 * CH;                    // [B][N][128] bf16
  unsigned short* x_t = zm  + (size_t)BATCH * NODES * CH;     // [B][N][128] bf16

  prep<<<96, 256, 0, stream>>>(W1, Wp, W2, W1b, Wpb, W2b);

  const int NT = (NODES + 63) / 64;         // 157 tiles of 64 nodes
  prep_x<<<dim3(NT, BATCH), 256, 0, stream>>>(x, x_t);
  fused_hz<<<512, 256, 0, stream>>>(W1b, b1, Wpb, bp, x_t, h_t, z_t);
  gmax_kernel<<<BATCH * NT, 256, 0, stream>>>(z_t, ei, zm);
  out_gemm<<<512, 256, 0, stream>>>(h_t, zm, W2b, b2, out);
}